// Round 1
// baseline (7933.466 us; speedup 1.0000x reference)
//
#include <hip/hip_runtime.h>
#include <math.h>

#define BM 64
#define BN 64
#define BK 16

// C = act(A[M,K] @ W[K,N] + bias), act = tanh
__global__ __launch_bounds__(256) void gemm_tanh_kernel(
    const float* __restrict__ A, const float* __restrict__ W,
    const float* __restrict__ bias, float* __restrict__ Out,
    int M, int N, int K)
{
    __shared__ float As[BK][BM + 1];   // +1 pad: avoid 16-way store conflicts
    __shared__ float Bs[BK][BN];
    const int tid = threadIdx.x;
    const int row0 = blockIdx.y * BM;
    const int col0 = blockIdx.x * BN;
    const int tx = tid & 15, ty = tid >> 4;
    const int aK = tid & 15, aR = tid >> 4;   // A tile: 64 rows x 16 k
    const int bC = tid & 63, bK = tid >> 6;   // B tile: 16 k x 64 cols

    float acc[4][4] = {};
    for (int kt = 0; kt < K; kt += BK) {
#pragma unroll
        for (int r = 0; r < 4; ++r)
            As[aK][aR + 16 * r] = A[(size_t)(row0 + aR + 16 * r) * K + kt + aK];
#pragma unroll
        for (int r = 0; r < 4; ++r)
            Bs[bK + 4 * r][bC] = W[(size_t)(kt + bK + 4 * r) * N + col0 + bC];
        __syncthreads();
#pragma unroll
        for (int kk = 0; kk < BK; ++kk) {
            float a[4], b[4];
#pragma unroll
            for (int i = 0; i < 4; ++i) a[i] = As[kk][ty * 4 + i];
#pragma unroll
            for (int j = 0; j < 4; ++j) b[j] = Bs[kk][tx * 4 + j];
#pragma unroll
            for (int i = 0; i < 4; ++i)
#pragma unroll
                for (int j = 0; j < 4; ++j)
                    acc[i][j] += a[i] * b[j];
        }
        __syncthreads();
    }
#pragma unroll
    for (int i = 0; i < 4; ++i) {
        const int row = row0 + ty * 4 + i;
#pragma unroll
        for (int j = 0; j < 4; ++j) {
            const int col = col0 + tx * 4 + j;
            Out[(size_t)row * N + col] = tanhf(acc[i][j] + bias[col]);
        }
    }
}

// F = Hd[M,K] @ W2[K,N] + bias; accOut = accIn + ca*F; ytmpOut = yIn + cy*F
__global__ __launch_bounds__(256) void gemm_stage_kernel(
    const float* __restrict__ A, const float* __restrict__ W,
    const float* __restrict__ bias,
    const float* __restrict__ accIn, float* __restrict__ accOut, float ca,
    const float* __restrict__ yIn, float* __restrict__ ytmpOut, float cy,
    int M, int N, int K)
{
    __shared__ float As[BK][BM + 1];
    __shared__ float Bs[BK][BN];
    const int tid = threadIdx.x;
    const int row0 = blockIdx.y * BM;
    const int col0 = blockIdx.x * BN;
    const int tx = tid & 15, ty = tid >> 4;
    const int aK = tid & 15, aR = tid >> 4;
    const int bC = tid & 63, bK = tid >> 6;

    float acc[4][4] = {};
    for (int kt = 0; kt < K; kt += BK) {
#pragma unroll
        for (int r = 0; r < 4; ++r)
            As[aK][aR + 16 * r] = A[(size_t)(row0 + aR + 16 * r) * K + kt + aK];
#pragma unroll
        for (int r = 0; r < 4; ++r)
            Bs[bK + 4 * r][bC] = W[(size_t)(kt + bK + 4 * r) * N + col0 + bC];
        __syncthreads();
#pragma unroll
        for (int kk = 0; kk < BK; ++kk) {
            float a[4], b[4];
#pragma unroll
            for (int i = 0; i < 4; ++i) a[i] = As[kk][ty * 4 + i];
#pragma unroll
            for (int j = 0; j < 4; ++j) b[j] = Bs[kk][tx * 4 + j];
#pragma unroll
            for (int i = 0; i < 4; ++i)
#pragma unroll
                for (int j = 0; j < 4; ++j)
                    acc[i][j] += a[i] * b[j];
        }
        __syncthreads();
    }
#pragma unroll
    for (int i = 0; i < 4; ++i) {
        const int row = row0 + ty * 4 + i;
#pragma unroll
        for (int j = 0; j < 4; ++j) {
            const int col = col0 + tx * 4 + j;
            const size_t idx = (size_t)row * N + col;
            const float F = acc[i][j] + bias[col];
            const float aI = accIn[idx];
            const float yI = yIn[idx];
            accOut[idx] = aI + ca * F;
            ytmpOut[idx] = yI + cy * F;
        }
    }
}

__global__ void gather_kernel(const float* __restrict__ Y,
                              const int* __restrict__ idx,
                              float* __restrict__ out, int B, int D, int Kc)
{
    int i = blockIdx.x * blockDim.x + threadIdx.x;
    if (i < B * Kc) {
        int b = i / Kc;
        out[i] = Y[(size_t)b * D + idx[i]];
    }
}

extern "C" void kernel_launch(void* const* d_in, const int* in_sizes, int n_in,
                              void* d_out, int out_size, void* d_ws, size_t ws_size,
                              hipStream_t stream)
{
    const float* x   = (const float*)d_in[0];
    const float* W1  = (const float*)d_in[1];
    const float* b1  = (const float*)d_in[2];
    const float* W2  = (const float*)d_in[3];
    const float* b2  = (const float*)d_in[4];
    const int* indices = (const int*)d_in[5];
    float* out = (float*)d_out;

    const int H = in_sizes[2];           // 1024
    const int D = in_sizes[4];           // 256
    const int B = in_sizes[0] / D;       // 4096
    const int K = in_sizes[5] / B;       // 128

    float* y    = (float*)d_ws;
    float* acc  = y    + (size_t)B * D;
    float* ytmp = acc  + (size_t)B * D;
    float* hid  = ytmp + (size_t)B * D;

    hipMemcpyAsync(y, x, sizeof(float) * (size_t)B * D,
                   hipMemcpyDeviceToDevice, stream);

    const int NS = 16;                   // RK4 steps; global err ~h^4 << tol
    const float h = 1.0f / NS;

    dim3 blk(256);
    dim3 g1(H / BN, B / BM);             // (16, 64)
    dim3 g2(D / BN, B / BM);             // (4, 64)

    for (int s = 0; s < NS; ++s) {
        // stage 1: k1 = f(y);   acc = y + h/6*k1;   ytmp = y + h/2*k1
        gemm_tanh_kernel<<<g1, blk, 0, stream>>>(y, W1, b1, hid, B, H, D);
        gemm_stage_kernel<<<g2, blk, 0, stream>>>(hid, W2, b2,
                                                  y, acc, h / 6.0f,
                                                  y, ytmp, h * 0.5f, B, D, H);
        // stage 2: k2 = f(ytmp); acc += h/3*k2;     ytmp = y + h/2*k2
        gemm_tanh_kernel<<<g1, blk, 0, stream>>>(ytmp, W1, b1, hid, B, H, D);
        gemm_stage_kernel<<<g2, blk, 0, stream>>>(hid, W2, b2,
                                                  acc, acc, h / 3.0f,
                                                  y, ytmp, h * 0.5f, B, D, H);
        // stage 3: k3 = f(ytmp); acc += h/3*k3;     ytmp = y + h*k3
        gemm_tanh_kernel<<<g1, blk, 0, stream>>>(ytmp, W1, b1, hid, B, H, D);
        gemm_stage_kernel<<<g2, blk, 0, stream>>>(hid, W2, b2,
                                                  acc, acc, h / 3.0f,
                                                  y, ytmp, h, B, D, H);
        // stage 4: k4 = f(ytmp); y = acc + h/6*k4
        gemm_tanh_kernel<<<g1, blk, 0, stream>>>(ytmp, W1, b1, hid, B, H, D);
        gemm_stage_kernel<<<g2, blk, 0, stream>>>(hid, W2, b2,
                                                  acc, y, h / 6.0f,
                                                  y, ytmp, 0.0f, B, D, H);
    }

    const int tot = B * K;
    gather_kernel<<<(tot + 255) / 256, 256, 0, stream>>>(y, indices, out, B, D, K);
}

// Round 2
// 2103.320 us; speedup vs baseline: 3.7719x; 3.7719x over previous
//
#include <hip/hip_runtime.h>
#include <math.h>

typedef __attribute__((ext_vector_type(8))) short bf16x8;
typedef __attribute__((ext_vector_type(4))) float f32x4;

static __device__ __forceinline__ unsigned short f2bf(float f) {
    unsigned u = __builtin_bit_cast(unsigned, f);
    unsigned r = (u + 0x7fffu + ((u >> 16) & 1u)) >> 16;   // RNE
    return (unsigned short)r;
}

// ---------------- GEMM1: Out[M][N] = tanh(Abf[M][K] @ BT[N][K]^T + bias), bf16 out
#define G1_BM 128
#define G1_BN 128
#define G1_BK 32
#define LDA1 40   // padded LDS row (elems); 80 B = 5*16 -> b128-aligned, 2-way banks

__global__ __launch_bounds__(256) void gemm1_tanh(
    const unsigned short* __restrict__ Abf,  // [M][K] bf16
    const unsigned short* __restrict__ BT,   // [N][K] bf16 (W1 transposed)
    const float* __restrict__ bias,          // [N]
    unsigned short* __restrict__ Out,        // [M][N] bf16
    int M, int N, int K)
{
    __shared__ unsigned short As[G1_BM * LDA1];
    __shared__ unsigned short Bs[G1_BN * LDA1];
    const int tid = threadIdx.x;
    const int lane = tid & 63;
    const int wave = tid >> 6;
    const int row0 = blockIdx.y * G1_BM;
    const int col0 = blockIdx.x * G1_BN;
    const int wm = (wave >> 1) * 64;
    const int wn = (wave & 1) * 64;
    const int quad = lane >> 4;
    const int l16 = lane & 15;
    const int sr = tid >> 2;          // 0..63
    const int sc = (tid & 3) * 8;     // 0,8,16,24

    f32x4 acc[4][4] = {};

    for (int kt = 0; kt < K; kt += G1_BK) {
#pragma unroll
        for (int p = 0; p < 2; ++p) {
            const int r = p * 64 + sr;
            const uint4 va = *(const uint4*)(&Abf[(size_t)(row0 + r) * K + kt + sc]);
            *(uint4*)(&As[r * LDA1 + sc]) = va;
            const uint4 vb = *(const uint4*)(&BT[(size_t)(col0 + r) * K + kt + sc]);
            *(uint4*)(&Bs[r * LDA1 + sc]) = vb;
        }
        __syncthreads();
        bf16x8 af[4], bfv[4];
#pragma unroll
        for (int mt = 0; mt < 4; ++mt)
            af[mt] = *(const bf16x8*)(&As[(wm + mt * 16 + l16) * LDA1 + quad * 8]);
#pragma unroll
        for (int nt = 0; nt < 4; ++nt)
            bfv[nt] = *(const bf16x8*)(&Bs[(wn + nt * 16 + l16) * LDA1 + quad * 8]);
#pragma unroll
        for (int mt = 0; mt < 4; ++mt)
#pragma unroll
            for (int nt = 0; nt < 4; ++nt)
                acc[mt][nt] = __builtin_amdgcn_mfma_f32_16x16x32_bf16(
                    af[mt], bfv[nt], acc[mt][nt], 0, 0, 0);
        __syncthreads();
    }
#pragma unroll
    for (int mt = 0; mt < 4; ++mt)
#pragma unroll
        for (int nt = 0; nt < 4; ++nt) {
            const int col = col0 + wn + nt * 16 + l16;
            const float bv = bias[col];
#pragma unroll
            for (int r = 0; r < 4; ++r) {
                const int row = row0 + wm + mt * 16 + quad * 4 + r;
                Out[(size_t)row * N + col] = f2bf(tanhf(acc[mt][nt][r] + bv));
            }
        }
}

// ---------------- GEMM2 + RK4 stage update
// F = Abf[M][K] @ BT[N][K]^T + bias
// out1 = in1 + c1*F ;  o2 = base2 + c2*F ; out2 = o2 (fp32); out2bf = bf16(o2)
#define G2_BM 64
#define G2_BN 64
#define G2_BK 64
#define LDA2 72   // 144 B = 9*16 aligned

__global__ __launch_bounds__(256) void gemm2_stage(
    const unsigned short* __restrict__ Abf,  // [M][K] bf16 (hid)
    const unsigned short* __restrict__ BT,   // [N][K] bf16 (W2 transposed)
    const float* __restrict__ bias,          // [N]
    const float* __restrict__ in1, float* __restrict__ out1, float c1,
    const float* __restrict__ base2, float* __restrict__ out2,
    unsigned short* __restrict__ out2bf, float c2,
    int M, int N, int K)
{
    __shared__ unsigned short As[G2_BM * LDA2];
    __shared__ unsigned short Bs[G2_BN * LDA2];
    const int tid = threadIdx.x;
    const int lane = tid & 63;
    const int wave = tid >> 6;
    const int row0 = blockIdx.y * G2_BM;
    const int col0 = blockIdx.x * G2_BN;
    const int wm = (wave >> 1) * 32;
    const int wn = (wave & 1) * 32;
    const int quad = lane >> 4;
    const int l16 = lane & 15;
    const int sr = tid >> 3;          // 0..31
    const int sc = (tid & 7) * 8;     // 0..56

    f32x4 acc[2][2] = {};

    for (int kt = 0; kt < K; kt += G2_BK) {
#pragma unroll
        for (int p = 0; p < 2; ++p) {
            const int r = p * 32 + sr;
            const uint4 va = *(const uint4*)(&Abf[(size_t)(row0 + r) * K + kt + sc]);
            *(uint4*)(&As[r * LDA2 + sc]) = va;
            const uint4 vb = *(const uint4*)(&BT[(size_t)(col0 + r) * K + kt + sc]);
            *(uint4*)(&Bs[r * LDA2 + sc]) = vb;
        }
        __syncthreads();
#pragma unroll
        for (int kc = 0; kc < 2; ++kc) {
            bf16x8 af[2], bfv[2];
#pragma unroll
            for (int mt = 0; mt < 2; ++mt)
                af[mt] = *(const bf16x8*)(&As[(wm + mt * 16 + l16) * LDA2 + kc * 32 + quad * 8]);
#pragma unroll
            for (int nt = 0; nt < 2; ++nt)
                bfv[nt] = *(const bf16x8*)(&Bs[(wn + nt * 16 + l16) * LDA2 + kc * 32 + quad * 8]);
#pragma unroll
            for (int mt = 0; mt < 2; ++mt)
#pragma unroll
                for (int nt = 0; nt < 2; ++nt)
                    acc[mt][nt] = __builtin_amdgcn_mfma_f32_16x16x32_bf16(
                        af[mt], bfv[nt], acc[mt][nt], 0, 0, 0);
        }
        __syncthreads();
    }
#pragma unroll
    for (int mt = 0; mt < 2; ++mt)
#pragma unroll
        for (int nt = 0; nt < 2; ++nt) {
            const int col = col0 + wn + nt * 16 + l16;
            const float bv = bias[col];
#pragma unroll
            for (int r = 0; r < 4; ++r) {
                const int row = row0 + wm + mt * 16 + quad * 4 + r;
                const size_t idx = (size_t)row * N + col;
                const float F = acc[mt][nt][r] + bv;
                out1[idx] = in1[idx] + c1 * F;
                const float o2 = base2[idx] + c2 * F;
                out2[idx] = o2;
                out2bf[idx] = f2bf(o2);
            }
        }
}

// ---------------- helpers
__global__ void cvt_copy_kernel(const float* __restrict__ x, float* __restrict__ y,
                                unsigned short* __restrict__ ybf, int n)
{
    int i = blockIdx.x * blockDim.x + threadIdx.x;
    if (i < n) { const float v = x[i]; y[i] = v; ybf[i] = f2bf(v); }
}

// W[R][C] fp32 -> WT[C][R] bf16
__global__ void transpose_bf_kernel(const float* __restrict__ W,
                                    unsigned short* __restrict__ WT, int R, int C)
{
    int i = blockIdx.x * blockDim.x + threadIdx.x;
    if (i < R * C) {
        const int r = i / C, c = i % C;
        WT[(size_t)c * R + r] = f2bf(W[i]);
    }
}

__global__ void gather_kernel(const float* __restrict__ Y,
                              const int* __restrict__ idx,
                              float* __restrict__ out, int B, int D, int Kc)
{
    int i = blockIdx.x * blockDim.x + threadIdx.x;
    if (i < B * Kc) {
        const int b = i / Kc;
        out[i] = Y[(size_t)b * D + idx[i]];
    }
}

extern "C" void kernel_launch(void* const* d_in, const int* in_sizes, int n_in,
                              void* d_out, int out_size, void* d_ws, size_t ws_size,
                              hipStream_t stream)
{
    const float* x  = (const float*)d_in[0];
    const float* W1 = (const float*)d_in[1];
    const float* b1 = (const float*)d_in[2];
    const float* W2 = (const float*)d_in[3];
    const float* b2 = (const float*)d_in[4];
    const int* indices = (const int*)d_in[5];
    float* out = (float*)d_out;

    const int H = in_sizes[2];        // 1024
    const int D = in_sizes[4];        // 256
    const int B = in_sizes[0] / D;    // 4096
    const int K = in_sizes[5] / B;    // 128

    const size_t BD = (size_t)B * D;
    const size_t BH = (size_t)B * H;

    char* ws = (char*)d_ws;
    float* y    = (float*)ws;                 ws += BD * 4;
    float* acc  = (float*)ws;                 ws += BD * 4;
    float* ytmp = (float*)ws;                 ws += BD * 4;
    unsigned short* ybf    = (unsigned short*)ws; ws += BD * 2;
    unsigned short* ytmpbf = (unsigned short*)ws; ws += BD * 2;
    unsigned short* hid    = (unsigned short*)ws; ws += BH * 2;
    unsigned short* W1T    = (unsigned short*)ws; ws += (size_t)H * D * 2;
    unsigned short* W2T    = (unsigned short*)ws; ws += (size_t)D * H * 2;

    // init: y/ybf from x; W1T,W2T bf16 transposes
    cvt_copy_kernel<<<(int)((BD + 255) / 256), 256, 0, stream>>>(x, y, ybf, (int)BD);
    transpose_bf_kernel<<<(int)(((size_t)D * H + 255) / 256), 256, 0, stream>>>(W1, W1T, D, H);
    transpose_bf_kernel<<<(int)(((size_t)H * D + 255) / 256), 256, 0, stream>>>(W2, W2T, H, D);

    const int NS = 16;
    const float h = 1.0f / NS;

    dim3 blk(256);
    dim3 g1(H / G1_BN, B / G1_BM);    // (8, 32)
    dim3 g2(D / G2_BN, B / G2_BM);    // (4, 64)

    for (int s = 0; s < NS; ++s) {
        // stage 1: k1=f(y);  acc = y + h/6 k1 ; ytmp = y + h/2 k1
        gemm1_tanh<<<g1, blk, 0, stream>>>(ybf, W1T, b1, hid, B, H, D);
        gemm2_stage<<<g2, blk, 0, stream>>>(hid, W2T, b2,
                                            y, acc, h / 6.0f,
                                            y, ytmp, ytmpbf, h * 0.5f, B, D, H);
        // stage 2: k2=f(ytmp); acc += h/3 k2 ; ytmp = y + h/2 k2
        gemm1_tanh<<<g1, blk, 0, stream>>>(ytmpbf, W1T, b1, hid, B, H, D);
        gemm2_stage<<<g2, blk, 0, stream>>>(hid, W2T, b2,
                                            acc, acc, h / 3.0f,
                                            y, ytmp, ytmpbf, h * 0.5f, B, D, H);
        // stage 3: k3=f(ytmp); acc += h/3 k3 ; ytmp = y + h k3
        gemm1_tanh<<<g1, blk, 0, stream>>>(ytmpbf, W1T, b1, hid, B, H, D);
        gemm2_stage<<<g2, blk, 0, stream>>>(hid, W2T, b2,
                                            acc, acc, h / 3.0f,
                                            y, ytmp, ytmpbf, h, B, D, H);
        // stage 4: k4=f(ytmp); y = acc + h/6 k4  (out1 is a dummy write to ytmp)
        gemm1_tanh<<<g1, blk, 0, stream>>>(ytmpbf, W1T, b1, hid, B, H, D);
        gemm2_stage<<<g2, blk, 0, stream>>>(hid, W2T, b2,
                                            acc, ytmp, 0.0f,
                                            acc, y, ybf, h / 6.0f, B, D, H);
    }

    const int tot = B * K;
    gather_kernel<<<(tot + 255) / 256, 256, 0, stream>>>(y, indices, out, B, D, K);
}

// Round 3
// 2004.114 us; speedup vs baseline: 3.9586x; 1.0495x over previous
//
#include <hip/hip_runtime.h>
#include <math.h>

typedef __attribute__((ext_vector_type(8))) short bf16x8;
typedef __attribute__((ext_vector_type(4))) float f32x4;

#define Dd 256
#define Hh 1024
#define Kk 128
#define NSTEP 16
#define LDI 264    // in_bf row stride (elems): 528 B -> 2-way banks on frag reads
#define LDH 1032   // hid row stride: 2064 B -> 2-way banks
#define LDY 260    // final-state fp32 row stride

static __device__ __forceinline__ unsigned short f2bf(float f) {
    unsigned u = __builtin_bit_cast(unsigned, f);
    unsigned r = (u + 0x7fffu + ((u >> 16) & 1u)) >> 16;   // RNE
    return (unsigned short)r;
}

static __device__ __forceinline__ float fast_tanh(float x) {
    // tanh(x) = 1 - 2/(e^{2x}+1); handles +-inf correctly via IEEE semantics
    const float e = __expf(2.0f * x);
    return 1.0f - 2.0f / (e + 1.0f);
}

// W[R][C] fp32 -> WT[C][R] bf16
__global__ void transpose_bf_kernel(const float* __restrict__ W,
                                    unsigned short* __restrict__ WT, int R, int C)
{
    int i = blockIdx.x * blockDim.x + threadIdx.x;
    if (i < R * C) {
        const int r = i / C, c = i % C;
        WT[(size_t)c * R + r] = f2bf(W[i]);
    }
}

// One block integrates 16 rows through all RK4 steps; weights streamed from L2.
__global__ __launch_bounds__(256, 1) void ode_fused(
    const float* __restrict__ x,
    const unsigned short* __restrict__ W1T,   // [H][D] bf16
    const float* __restrict__ b1,
    const unsigned short* __restrict__ W2T,   // [D][H] bf16
    const float* __restrict__ b2,
    const int* __restrict__ indices,
    float* __restrict__ out)
{
    __shared__ __align__(16) unsigned short in_bf[16 * LDI];  // f input, bf16
    __shared__ __align__(16) unsigned short hid[16 * LDH];    // hidden, bf16

    const int tid  = threadIdx.x;
    const int lane = tid & 63;
    const int w    = tid >> 6;      // wave 0..3
    const int quad = lane >> 4;
    const int l16  = lane & 15;
    const int row0 = blockIdx.x * 16;

    // This wave owns output cols [w*64, w*64+64). Lane element (ct, r):
    //   col = w*64 + ct*16 + l16, row = quad*4 + r   (MFMA C/D layout)
    float yv[4][4];   // integration state y (fp32, registers)
    float av[4][4];   // RK4 accumulator

    // cache biases in registers (persistent across all evals)
    float b1f[16];
#pragma unroll
    for (int ct = 0; ct < 16; ++ct) b1f[ct] = b1[w * 256 + ct * 16 + l16];
    float b2f[4];
#pragma unroll
    for (int ct = 0; ct < 4; ++ct) b2f[ct] = b2[w * 64 + ct * 16 + l16];

    // init y from x; seed in_bf
#pragma unroll
    for (int ct = 0; ct < 4; ++ct) {
        const int col = w * 64 + ct * 16 + l16;
#pragma unroll
        for (int r = 0; r < 4; ++r) {
            const int row = quad * 4 + r;
            const float v = x[(size_t)(row0 + row) * Dd + col];
            yv[ct][r] = v;
            in_bf[row * LDI + col] = f2bf(v);
        }
    }
    __syncthreads();

    const float h  = 1.0f / NSTEP;
    const float h6 = h / 6.0f, h3 = h / 3.0f, h2 = h * 0.5f;

    // per-lane weight base pointers (b-frag: n = l16 row, k = quad*8..+8)
    const unsigned short* w1p = W1T + (size_t)(w * 256 + l16) * Dd + quad * 8;
    const unsigned short* w2p = W2T + (size_t)(w * 64 + l16) * Hh + quad * 8;

    for (int s = 0; s < NSTEP; ++s) {
#pragma unroll 1
        for (int e = 0; e < 4; ++e) {
            // ---- GEMM1: hid[16][w*256..+256] = tanh(in_bf @ W1 + b1)
            bf16x8 afr[8];
#pragma unroll
            for (int kst = 0; kst < 8; ++kst)
                afr[kst] = *(const bf16x8*)(&in_bf[l16 * LDI + kst * 32 + quad * 8]);

#pragma unroll 2
            for (int ctp = 0; ctp < 8; ++ctp) {
                const int ct0 = ctp * 2, ct1 = ct0 + 1;
                bf16x8 bv0[8], bv1[8];
#pragma unroll
                for (int kst = 0; kst < 8; ++kst) {
                    bv0[kst] = *(const bf16x8*)(w1p + (size_t)ct0 * 16 * Dd + kst * 32);
                    bv1[kst] = *(const bf16x8*)(w1p + (size_t)ct1 * 16 * Dd + kst * 32);
                }
                f32x4 ac0 = {0.f, 0.f, 0.f, 0.f}, ac1 = {0.f, 0.f, 0.f, 0.f};
#pragma unroll
                for (int kst = 0; kst < 8; ++kst) {
                    ac0 = __builtin_amdgcn_mfma_f32_16x16x32_bf16(afr[kst], bv0[kst], ac0, 0, 0, 0);
                    ac1 = __builtin_amdgcn_mfma_f32_16x16x32_bf16(afr[kst], bv1[kst], ac1, 0, 0, 0);
                }
                const int col0 = w * 256 + ct0 * 16 + l16;
#pragma unroll
                for (int r = 0; r < 4; ++r) {
                    const int row = quad * 4 + r;
                    hid[row * LDH + col0]      = f2bf(fast_tanh(ac0[r] + b1f[ct0]));
                    hid[row * LDH + col0 + 16] = f2bf(fast_tanh(ac1[r] + b1f[ct1]));
                }
            }
            __syncthreads();

            // ---- GEMM2: F[16][w*64..+64] = hid @ W2 + b2 ; RK4 stage update
#pragma unroll 1
            for (int ct = 0; ct < 4; ++ct) {
                f32x4 ac = {0.f, 0.f, 0.f, 0.f};
#pragma unroll 2
                for (int kseg = 0; kseg < 4; ++kseg) {
                    bf16x8 bv[8], af2[8];
#pragma unroll
                    for (int kst = 0; kst < 8; ++kst) {
                        const int k = kseg * 256 + kst * 32;
                        af2[kst] = *(const bf16x8*)(&hid[l16 * LDH + k + quad * 8]);
                        bv[kst]  = *(const bf16x8*)(w2p + (size_t)ct * 16 * Hh + k);
                    }
#pragma unroll
                    for (int kst = 0; kst < 8; ++kst)
                        ac = __builtin_amdgcn_mfma_f32_16x16x32_bf16(af2[kst], bv[kst], ac, 0, 0, 0);
                }
                const int col = w * 64 + ct * 16 + l16;
#pragma unroll
                for (int r = 0; r < 4; ++r) {
                    const float F = ac[r] + b2f[ct];
                    float tmp;
                    if (e == 0)      { av[ct][r] = yv[ct][r] + h6 * F; tmp = yv[ct][r] + h2 * F; }
                    else if (e == 1) { av[ct][r] += h3 * F;            tmp = yv[ct][r] + h2 * F; }
                    else if (e == 2) { av[ct][r] += h3 * F;            tmp = yv[ct][r] + h  * F; }
                    else             { yv[ct][r] = av[ct][r] + h6 * F; tmp = yv[ct][r]; }
                    in_bf[(quad * 4 + r) * LDI + col] = f2bf(tmp);
                }
            }
            __syncthreads();
        }
    }

    // final state -> LDS (reuse hid) -> gather
    float* yf = (float*)hid;
#pragma unroll
    for (int ct = 0; ct < 4; ++ct) {
        const int col = w * 64 + ct * 16 + l16;
#pragma unroll
        for (int r = 0; r < 4; ++r)
            yf[(quad * 4 + r) * LDY + col] = yv[ct][r];
    }
    __syncthreads();

    for (int i = tid; i < 16 * Kk; i += 256) {
        const int row = i >> 7;          // i / 128
        const int kc  = i & (Kk - 1);
        const int gi  = (row0 + row) * Kk + kc;
        out[gi] = yf[row * LDY + indices[gi]];
    }
}

extern "C" void kernel_launch(void* const* d_in, const int* in_sizes, int n_in,
                              void* d_out, int out_size, void* d_ws, size_t ws_size,
                              hipStream_t stream)
{
    const float* x  = (const float*)d_in[0];
    const float* W1 = (const float*)d_in[1];
    const float* b1 = (const float*)d_in[2];
    const float* W2 = (const float*)d_in[3];
    const float* b2 = (const float*)d_in[4];
    const int* indices = (const int*)d_in[5];
    float* out = (float*)d_out;

    const int H = in_sizes[2];        // 1024
    const int D = in_sizes[4];        // 256
    const int B = in_sizes[0] / D;    // 4096

    unsigned short* W1T = (unsigned short*)d_ws;                 // [H][D]
    unsigned short* W2T = W1T + (size_t)H * D;                   // [D][H]

    transpose_bf_kernel<<<(int)(((size_t)D * H + 255) / 256), 256, 0, stream>>>(W1, W1T, D, H);
    transpose_bf_kernel<<<(int)(((size_t)H * D + 255) / 256), 256, 0, stream>>>(W2, W2T, H, D);

    ode_fused<<<B / 16, 256, 0, stream>>>(x, W1T, b1, W2T, b2, indices, out);
}

// Round 4
// 987.667 us; speedup vs baseline: 8.0325x; 2.0291x over previous
//
#include <hip/hip_runtime.h>
#include <math.h>

typedef __attribute__((ext_vector_type(8))) short bf16x8;
typedef __attribute__((ext_vector_type(4))) float f32x4;

#define Dd 256
#define Hh 1024
#define Kk 128
#define NSTEP 8
#define LDI 264    // in_bf row stride (elems): 528 B -> conflict-free b128 frag reads
#define LDH 1032   // hid row stride: 2064 B -> same (516 dw % 32 == 4)
#define LDY 260    // final-state fp32 row stride

static __device__ __forceinline__ unsigned short f2bf(float f) {
    unsigned u = __builtin_bit_cast(unsigned, f);
    unsigned r = (u + 0x7fffu + ((u >> 16) & 1u)) >> 16;   // RNE
    return (unsigned short)r;
}

static __device__ __forceinline__ float fast_tanh(float x) {
    const float e = __expf(2.0f * x);
    return 1.0f - 2.0f / (e + 1.0f);
}

// W[R][C] fp32 -> WT[C][R] bf16
__global__ void transpose_bf_kernel(const float* __restrict__ W,
                                    unsigned short* __restrict__ WT, int R, int C)
{
    int i = blockIdx.x * blockDim.x + threadIdx.x;
    if (i < R * C) {
        const int r = i / C, c = i % C;
        WT[(size_t)c * R + r] = f2bf(W[i]);
    }
}

// One block (16 waves = 4 waves/SIMD) integrates 16 rows through all RK4 steps.
// GEMM1: wave w owns hid cols [w*64, +64). GEMM2: wave w owns state cols [w*16, +16).
__global__ __launch_bounds__(1024) void ode_fused(
    const float* __restrict__ x,
    const unsigned short* __restrict__ W1T,   // [H][D] bf16
    const float* __restrict__ b1,
    const unsigned short* __restrict__ W2T,   // [D][H] bf16
    const float* __restrict__ b2,
    const int* __restrict__ indices,
    float* __restrict__ out)
{
    __shared__ __align__(16) unsigned short in_bf[16 * LDI];
    __shared__ __align__(16) unsigned short hid[16 * LDH];

    const int tid  = threadIdx.x;
    const int lane = tid & 63;
    const int w    = tid >> 6;      // wave 0..15
    const int quad = lane >> 4;
    const int l16  = lane & 15;
    const int row0 = blockIdx.x * 16;

    float yv[4];    // state, col = w*16+l16, row = quad*4+r
    float av[4];    // RK4 accumulator

    float b1f[4];
#pragma unroll
    for (int ct = 0; ct < 4; ++ct) b1f[ct] = b1[w * 64 + ct * 16 + l16];
    const float b2f = b2[w * 16 + l16];

    {
        const int col = w * 16 + l16;
#pragma unroll
        for (int r = 0; r < 4; ++r) {
            const int row = quad * 4 + r;
            const float v = x[(size_t)(row0 + row) * Dd + col];
            yv[r] = v;
            in_bf[row * LDI + col] = f2bf(v);
        }
    }
    __syncthreads();

    const float h  = 1.0f / NSTEP;
    const float h6 = h / 6.0f, h3 = h / 3.0f, h2 = h * 0.5f;

    const unsigned short* w1p = W1T + (size_t)(w * 64 + l16) * Dd + quad * 8;
    const unsigned short* w2p = W2T + (size_t)(w * 16 + l16) * Hh + quad * 8;

#pragma unroll 1
    for (int s = 0; s < NSTEP; ++s) {
#pragma unroll 1
        for (int e = 0; e < 4; ++e) {
            // ---- GEMM1: hid[16][w*64..+64] = tanh(in_bf @ W1 + b1)
            bf16x8 afr[8];
#pragma unroll
            for (int kst = 0; kst < 8; ++kst)
                afr[kst] = *(const bf16x8*)(&in_bf[l16 * LDI + kst * 32 + quad * 8]);

#pragma unroll
            for (int ctp = 0; ctp < 2; ++ctp) {
                const int ct0 = ctp * 2, ct1 = ct0 + 1;
                bf16x8 bv0[8], bv1[8];
#pragma unroll
                for (int kst = 0; kst < 8; ++kst) {
                    bv0[kst] = *(const bf16x8*)(w1p + (size_t)ct0 * 16 * Dd + kst * 32);
                    bv1[kst] = *(const bf16x8*)(w1p + (size_t)ct1 * 16 * Dd + kst * 32);
                }
                f32x4 ac0 = {0.f, 0.f, 0.f, 0.f}, ac1 = {0.f, 0.f, 0.f, 0.f};
#pragma unroll
                for (int kst = 0; kst < 8; ++kst) {
                    ac0 = __builtin_amdgcn_mfma_f32_16x16x32_bf16(afr[kst], bv0[kst], ac0, 0, 0, 0);
                    ac1 = __builtin_amdgcn_mfma_f32_16x16x32_bf16(afr[kst], bv1[kst], ac1, 0, 0, 0);
                }
                const int col0 = w * 64 + ct0 * 16 + l16;
#pragma unroll
                for (int r = 0; r < 4; ++r) {
                    const int row = quad * 4 + r;
                    hid[row * LDH + col0]      = f2bf(fast_tanh(ac0[r] + b1f[ct0]));
                    hid[row * LDH + col0 + 16] = f2bf(fast_tanh(ac1[r] + b1f[ct1]));
                }
            }
            __syncthreads();

            // ---- GEMM2: F[16][w*16..+16] = hid @ W2 + b2 ; RK4 update
            f32x4 aca = {0.f, 0.f, 0.f, 0.f}, acb = {0.f, 0.f, 0.f, 0.f};
#pragma unroll
            for (int ksp = 0; ksp < 2; ++ksp) {
                bf16x8 a2a[8], b2a[8], a2b[8], b2b[8];
#pragma unroll
                for (int kst = 0; kst < 8; ++kst) {
                    const int ka = ksp * 512 + kst * 32;
                    const int kb = ka + 256;
                    a2a[kst] = *(const bf16x8*)(&hid[l16 * LDH + ka + quad * 8]);
                    b2a[kst] = *(const bf16x8*)(w2p + ka);
                    a2b[kst] = *(const bf16x8*)(&hid[l16 * LDH + kb + quad * 8]);
                    b2b[kst] = *(const bf16x8*)(w2p + kb);
                }
#pragma unroll
                for (int kst = 0; kst < 8; ++kst) {
                    aca = __builtin_amdgcn_mfma_f32_16x16x32_bf16(a2a[kst], b2a[kst], aca, 0, 0, 0);
                    acb = __builtin_amdgcn_mfma_f32_16x16x32_bf16(a2b[kst], b2b[kst], acb, 0, 0, 0);
                }
            }
            {
                const int col = w * 16 + l16;
#pragma unroll
                for (int r = 0; r < 4; ++r) {
                    const float F = aca[r] + acb[r] + b2f;
                    float tmp;
                    if (e == 0)      { av[r] = yv[r] + h6 * F; tmp = yv[r] + h2 * F; }
                    else if (e == 1) { av[r] += h3 * F;        tmp = yv[r] + h2 * F; }
                    else if (e == 2) { av[r] += h3 * F;        tmp = yv[r] + h  * F; }
                    else             { yv[r] = av[r] + h6 * F; tmp = yv[r]; }
                    in_bf[(quad * 4 + r) * LDI + col] = f2bf(tmp);
                }
            }
            __syncthreads();
        }
    }

    // final state -> LDS (reuse hid) -> gather
    float* yf = (float*)hid;
    {
        const int col = w * 16 + l16;
#pragma unroll
        for (int r = 0; r < 4; ++r)
            yf[(quad * 4 + r) * LDY + col] = yv[r];
    }
    __syncthreads();

    for (int i = tid; i < 16 * Kk; i += 1024) {
        const int row = i >> 7;
        const int kc  = i & (Kk - 1);
        const int gi  = (row0 + row) * Kk + kc;
        out[gi] = yf[row * LDY + indices[gi]];
    }
}

extern "C" void kernel_launch(void* const* d_in, const int* in_sizes, int n_in,
                              void* d_out, int out_size, void* d_ws, size_t ws_size,
                              hipStream_t stream)
{
    const float* x  = (const float*)d_in[0];
    const float* W1 = (const float*)d_in[1];
    const float* b1 = (const float*)d_in[2];
    const float* W2 = (const float*)d_in[3];
    const float* b2 = (const float*)d_in[4];
    const int* indices = (const int*)d_in[5];
    float* out = (float*)d_out;

    const int H = in_sizes[2];        // 1024
    const int D = in_sizes[4];        // 256
    const int B = in_sizes[0] / D;    // 4096

    unsigned short* W1T = (unsigned short*)d_ws;                 // [H][D]
    unsigned short* W2T = W1T + (size_t)H * D;                   // [D][H]

    transpose_bf_kernel<<<(int)(((size_t)D * H + 255) / 256), 256, 0, stream>>>(W1, W1T, D, H);
    transpose_bf_kernel<<<(int)(((size_t)H * D + 255) / 256), 256, 0, stream>>>(W2, W2T, H, D);

    ode_fused<<<B / 16, 1024, 0, stream>>>(x, W1T, b1, W2T, b2, indices, out);
}